// Round 4
// baseline (449.039 us; speedup 1.0000x reference)
//
#include <hip/hip_runtime.h>
#include <hip/hip_bf16.h>
#include <stdint.h>

// Problem constants: B=2, S=2048, D=1024, H=16, dk=64
#define NB 2
#define NS 2048
#define ND 1024
#define NH 16
#define DKH 64

typedef __attribute__((ext_vector_type(8))) short bf16x8;   // 8 bf16 = 4 VGPRs
typedef __attribute__((ext_vector_type(4))) float f32x4;
typedef __attribute__((ext_vector_type(8))) unsigned short u16x8;

__device__ __forceinline__ unsigned short f2bf(float x) {
  union { float f; unsigned int u; } c; c.f = x;
  unsigned int u = c.u;
  unsigned int r = (u + 0x7fffu + ((u >> 16) & 1u)) >> 16;  // round-nearest-even
  return (unsigned short)r;
}

// async global->LDS, 16B per lane; LDS dest is wave-uniform base + lane*16
#define GLOAD_LDS16(gp, lp)                                                     \
  __builtin_amdgcn_global_load_lds(                                             \
      (const __attribute__((address_space(1))) void*)(gp),                      \
      (__attribute__((address_space(3))) void*)(lp), 16, 0, 0)

// ---------------------------------------------------------------- convert ----
__global__ __launch_bounds__(256) void cvt_kernel(const float* __restrict__ src,
                                                  unsigned short* __restrict__ dst,
                                                  int n8) {
  for (int i = blockIdx.x * blockDim.x + threadIdx.x; i < n8;
       i += gridDim.x * blockDim.x) {
    const float4* sp = reinterpret_cast<const float4*>(src) + (size_t)i * 2;
    float4 a = sp[0], b = sp[1];
    u16x8 o;
    o[0] = f2bf(a.x); o[1] = f2bf(a.y); o[2] = f2bf(a.z); o[3] = f2bf(a.w);
    o[4] = f2bf(b.x); o[5] = f2bf(b.y); o[6] = f2bf(b.z); o[7] = f2bf(b.w);
    reinterpret_cast<u16x8*>(dst)[i] = o;
  }
}

// mask [B,1,S,S] int32 -> bitmask, 1 bit per (q,k); word = 64 consecutive k
__global__ __launch_bounds__(256) void maskbits_kernel(const int* __restrict__ mask,
                                                       unsigned long long* __restrict__ bits) {
  int i = blockIdx.x * blockDim.x + threadIdx.x;  // one u64 word per thread
  const int4* p = reinterpret_cast<const int4*>(mask + (size_t)i * 64);
  unsigned long long w = 0;
#pragma unroll
  for (int j = 0; j < 16; j++) {
    int4 v = p[j];
    unsigned long long nib = (v.x ? 1ull : 0) | (v.y ? 2ull : 0) |
                             (v.z ? 4ull : 0) | (v.w ? 8ull : 0);
    w |= nib << (j * 4);
  }
  bits[i] = w;
}

// ------------------------------------------------------------- GEMM core ----
// C[128x128] = A[128xK] * Bt[128xK]^T ; K = 1024. m97 structure: BK=64,
// global_load_lds width 16, 4 waves (2x2), each wave 64x64 = 4x4 16x16 frags.
// SWAP=true computes D^T fragments (operands swapped) for the V-transpose path.
template <bool SWAP>
__device__ __forceinline__ void gemm_core(const unsigned short* __restrict__ A,
                                          const unsigned short* __restrict__ Bt,
                                          int m0, int n0,
                                          unsigned short* As, unsigned short* Bs,
                                          f32x4 acc[4][4]) {
  const int tid = threadIdx.x;
  const int w = tid >> 6;
  const int l = tid & 63;
  const int wr = w >> 1, wc = w & 1;
  const int lr = l & 15, lg = l >> 4;

#pragma unroll
  for (int i = 0; i < 4; i++)
#pragma unroll
    for (int j = 0; j < 4; j++) acc[i][j] = (f32x4){0.f, 0.f, 0.f, 0.f};

  for (int k0 = 0; k0 < ND; k0 += 64) {
    __syncthreads();  // previous tile's compute done before overwrite
#pragma unroll
    for (int j = 0; j < 4; j++) {
      int flat = j * 2048 + tid * 8;          // elem index in 128x64 tile
      int row = flat >> 6, col = flat & 63;
      GLOAD_LDS16(A + (size_t)(m0 + row) * ND + k0 + col, As + j * 2048 + w * 512);
      GLOAD_LDS16(Bt + (size_t)(n0 + row) * ND + k0 + col, Bs + j * 2048 + w * 512);
    }
    __syncthreads();  // compiler emits vmcnt(0) drain before barrier
#pragma unroll
    for (int ks = 0; ks < 2; ks++) {
      bf16x8 av[4], bv[4];
#pragma unroll
      for (int mi = 0; mi < 4; mi++)
        av[mi] = *reinterpret_cast<const bf16x8*>(As + (wr * 64 + mi * 16 + lr) * 64 + ks * 32 + lg * 8);
#pragma unroll
      for (int ni = 0; ni < 4; ni++)
        bv[ni] = *reinterpret_cast<const bf16x8*>(Bs + (wc * 64 + ni * 16 + lr) * 64 + ks * 32 + lg * 8);
#pragma unroll
      for (int mi = 0; mi < 4; mi++)
#pragma unroll
        for (int ni = 0; ni < 4; ni++)
          acc[mi][ni] = SWAP
              ? __builtin_amdgcn_mfma_f32_16x16x32_bf16(bv[ni], av[mi], acc[mi][ni], 0, 0, 0)
              : __builtin_amdgcn_mfma_f32_16x16x32_bf16(av[mi], bv[ni], acc[mi][ni], 0, 0, 0);
    }
  }
}

// QKV projection: z=0 Q, z=1 K (store [B,H,S,dk]); z=2 V (store transposed [B,H,dk,S])
__global__ __launch_bounds__(256, 2) void qkv_kernel(
    const unsigned short* __restrict__ Xq, const unsigned short* __restrict__ Xk,
    const unsigned short* __restrict__ Xv, const unsigned short* __restrict__ Wq,
    const unsigned short* __restrict__ Wk, const unsigned short* __restrict__ Wv,
    const float* __restrict__ bq, const float* __restrict__ bk,
    const float* __restrict__ bv, unsigned short* __restrict__ Qo,
    unsigned short* __restrict__ Ko, unsigned short* __restrict__ Vt) {
  __shared__ __align__(16) unsigned short As[128 * 64];
  __shared__ __align__(16) unsigned short Bs[128 * 64];
  const int z = blockIdx.z;
  const unsigned short* X = (z == 0) ? Xq : (z == 1) ? Xk : Xv;
  const unsigned short* W = (z == 0) ? Wq : (z == 1) ? Wk : Wv;
  const float* bias = (z == 0) ? bq : (z == 1) ? bk : bv;
  const int m0 = blockIdx.y * 128, n0 = blockIdx.x * 128;
  const int tid = threadIdx.x;
  const int w = tid >> 6, l = tid & 63;
  const int wr = w >> 1, wc = w & 1, lr = l & 15, lg = l >> 4;
  f32x4 acc[4][4];

  if (z < 2) {
    gemm_core<false>(X, W, m0, n0, As, Bs, acc);
    unsigned short* O = (z == 0) ? Qo : Ko;
#pragma unroll
    for (int mi = 0; mi < 4; mi++)
#pragma unroll
      for (int ni = 0; ni < 4; ni++)
#pragma unroll
        for (int r = 0; r < 4; r++) {
          int mrow = m0 + wr * 64 + mi * 16 + lg * 4 + r;   // b*S+s
          int ncol = n0 + wc * 64 + ni * 16 + lr;           // h*dk+d
          float y = acc[mi][ni][r] + bias[ncol];
          int bb = mrow >> 11, s = mrow & 2047, hh = ncol >> 6, d = ncol & 63;
          O[(((size_t)(bb * NH + hh)) * NS + s) * DKH + d] = f2bf(y);
        }
  } else {
    gemm_core<true>(X, W, m0, n0, As, Bs, acc);  // D fragments are transposed
#pragma unroll
    for (int mi = 0; mi < 4; mi++)
#pragma unroll
      for (int ni = 0; ni < 4; ni++)
#pragma unroll
        for (int r = 0; r < 4; r++) {
          int ncol = n0 + wc * 64 + ni * 16 + lg * 4 + r;   // output feature
          int mrow = m0 + wr * 64 + mi * 16 + lr;           // b*S+s (lane-consecutive)
          float y = acc[mi][ni][r] + bias[ncol];
          int bb = mrow >> 11, s = mrow & 2047, hh = ncol >> 6, d = ncol & 63;
          Vt[(((size_t)(bb * NH + hh)) * DKH + d) * NS + s] = f2bf(y);
        }
  }
}

// output projection: out = O @ wo^T + bo, fp32 out
__global__ __launch_bounds__(256, 2) void outproj_kernel(
    const unsigned short* __restrict__ Oin, const unsigned short* __restrict__ Wo,
    const float* __restrict__ bo, float* __restrict__ out) {
  __shared__ __align__(16) unsigned short As[128 * 64];
  __shared__ __align__(16) unsigned short Bs[128 * 64];
  const int m0 = blockIdx.y * 128, n0 = blockIdx.x * 128;
  const int tid = threadIdx.x;
  const int w = tid >> 6, l = tid & 63;
  const int wr = w >> 1, wc = w & 1, lr = l & 15, lg = l >> 4;
  f32x4 acc[4][4];
  gemm_core<false>(Oin, Wo, m0, n0, As, Bs, acc);
#pragma unroll
  for (int mi = 0; mi < 4; mi++)
#pragma unroll
    for (int ni = 0; ni < 4; ni++)
#pragma unroll
      for (int r = 0; r < 4; r++) {
        int mrow = m0 + wr * 64 + mi * 16 + lg * 4 + r;
        int ncol = n0 + wc * 64 + ni * 16 + lr;
        out[(size_t)mrow * ND + ncol] = acc[mi][ni][r] + bo[ncol];
      }
}

// ----------------------------------------------------------- attention ------
// one block per (b, h, 128 q-rows); 4 independent waves, 32 q-rows each.
// flash: loop K-tiles of 64, online softmax, P via per-wave LDS transpose.
__global__ __launch_bounds__(256, 2) void attn_kernel(
    const unsigned short* __restrict__ Qg, const unsigned short* __restrict__ Kg,
    const unsigned short* __restrict__ Vtg,
    const unsigned long long* __restrict__ mbits,
    unsigned short* __restrict__ Og) {
  __shared__ __align__(16) unsigned short Plds[4][32 * 72];  // pad 72 vs 64: bank spread
  const int tid = threadIdx.x;
  const int w = tid >> 6, l = tid & 63;
  const int lr = l & 15, lg = l >> 4;
  const int b = blockIdx.z, h = blockIdx.y;
  const int qbase = blockIdx.x * 128 + w * 32;

  const unsigned short* Qh = Qg + ((size_t)(b * NH + h)) * NS * DKH;
  const unsigned short* Kh = Kg + ((size_t)(b * NH + h)) * NS * DKH;
  const unsigned short* Vth = Vtg + ((size_t)(b * NH + h)) * DKH * NS;
  unsigned short* Pw = Plds[w];

  // Q fragments hoisted (A-operand): [m][ks]
  bf16x8 aQ[2][2];
#pragma unroll
  for (int m = 0; m < 2; m++)
#pragma unroll
    for (int ks = 0; ks < 2; ks++)
      aQ[m][ks] = *reinterpret_cast<const bf16x8*>(
          Qh + (qbase + m * 16 + lr) * DKH + ks * 32 + lg * 8);

  f32x4 accO[2][4];
  float mrun[2][4], lrun[2][4];
#pragma unroll
  for (int m = 0; m < 2; m++)
#pragma unroll
    for (int n = 0; n < 4; n++) accO[m][n] = (f32x4){0.f, 0.f, 0.f, 0.f};
#pragma unroll
  for (int m = 0; m < 2; m++)
#pragma unroll
    for (int r = 0; r < 4; r++) { mrun[m][r] = -3.0e38f; lrun[m][r] = 0.f; }

  for (int kk0 = 0; kk0 < NS; kk0 += 64) {
    // ---- QK^T on this 64-col tile
    f32x4 s[2][4];
#pragma unroll
    for (int m = 0; m < 2; m++)
#pragma unroll
      for (int n = 0; n < 4; n++) s[m][n] = (f32x4){0.f, 0.f, 0.f, 0.f};
#pragma unroll
    for (int ks = 0; ks < 2; ks++) {
      bf16x8 kb[4];
#pragma unroll
      for (int n = 0; n < 4; n++)
        kb[n] = *reinterpret_cast<const bf16x8*>(
            Kh + (kk0 + n * 16 + lr) * DKH + ks * 32 + lg * 8);
#pragma unroll
      for (int m = 0; m < 2; m++)
#pragma unroll
        for (int n = 0; n < 4; n++)
          s[m][n] = __builtin_amdgcn_mfma_f32_16x16x32_bf16(aQ[m][ks], kb[n], s[m][n], 0, 0, 0);
    }
    // ---- scale + mask  (D layout: row=lg*4+r, col=lr within 16x16 frag)
#pragma unroll
    for (int m = 0; m < 2; m++)
#pragma unroll
      for (int r = 0; r < 4; r++) {
        int qa = qbase + m * 16 + lg * 4 + r;
        unsigned long long w64 = mbits[(size_t)(b * NS + qa) * (NS / 64) + (kk0 >> 6)];
#pragma unroll
        for (int n = 0; n < 4; n++) {
          float v = s[m][n][r] * 0.125f;  // 1/sqrt(64)
          if (!((w64 >> (n * 16 + lr)) & 1ull)) v = -1e9f;
          s[m][n][r] = v;
        }
      }
    // ---- online softmax (row reduce across the 16 lanes of a row group)
#pragma unroll
    for (int m = 0; m < 2; m++)
#pragma unroll
      for (int r = 0; r < 4; r++) {
        float v = fmaxf(fmaxf(s[m][0][r], s[m][1][r]), fmaxf(s[m][2][r], s[m][3][r]));
        v = fmaxf(v, __shfl_xor(v, 1, 16));
        v = fmaxf(v, __shfl_xor(v, 2, 16));
        v = fmaxf(v, __shfl_xor(v, 4, 16));
        v = fmaxf(v, __shfl_xor(v, 8, 16));
        float mn = fmaxf(mrun[m][r], v);
        float corr = __expf(mrun[m][r] - mn);
        mrun[m][r] = mn;
        float ps = 0.f;
#pragma unroll
        for (int n = 0; n < 4; n++) {
          float p = __expf(s[m][n][r] - mn);
          s[m][n][r] = p;
          ps += p;
        }
        ps += __shfl_xor(ps, 1, 16);
        ps += __shfl_xor(ps, 2, 16);
        ps += __shfl_xor(ps, 4, 16);
        ps += __shfl_xor(ps, 8, 16);
        lrun[m][r] = lrun[m][r] * corr + ps;
#pragma unroll
        for (int n = 0; n < 4; n++) accO[m][n][r] *= corr;
      }
    // ---- P -> LDS (bf16), per-wave private tile: no block barrier needed
#pragma unroll
    for (int m = 0; m < 2; m++)
#pragma unroll
      for (int n = 0; n < 4; n++)
#pragma unroll
        for (int r = 0; r < 4; r++)
          Pw[(m * 16 + lg * 4 + r) * 72 + n * 16 + lr] = f2bf(s[m][n][r]);
    // ---- PV: A=P (from LDS), B=V^T rows (contiguous in k)
#pragma unroll
    for (int ks = 0; ks < 2; ks++) {
      bf16x8 pa[2], vb[4];
#pragma unroll
      for (int m = 0; m < 2; m++)
        pa[m] = *reinterpret_cast<const bf16x8*>(Pw + (m * 16 + lr) * 72 + ks * 32 + lg * 8);
#pragma unroll
      for (int n = 0; n < 4; n++)
        vb[n] = *reinterpret_cast<const bf16x8*>(
            Vth + (n * 16 + lr) * NS + kk0 + ks * 32 + lg * 8);
#pragma unroll
      for (int m = 0; m < 2; m++)
#pragma unroll
        for (int n = 0; n < 4; n++)
          accO[m][n] = __builtin_amdgcn_mfma_f32_16x16x32_bf16(pa[m], vb[n], accO[m][n], 0, 0, 0);
    }
  }
  // ---- epilogue: normalize, store bf16 O[b, s, h*64+d]
#pragma unroll
  for (int m = 0; m < 2; m++)
#pragma unroll
    for (int r = 0; r < 4; r++) {
      float inv = 1.0f / lrun[m][r];
      int qa = qbase + m * 16 + lg * 4 + r;
#pragma unroll
      for (int n = 0; n < 4; n++) {
        int d = n * 16 + lr;
        Og[((size_t)(b * NS + qa)) * ND + h * DKH + d] = f2bf(accO[m][n][r] * inv);
      }
    }
}

// ---------------------------------------------------------------- launch ----
extern "C" void kernel_launch(void* const* d_in, const int* in_sizes, int n_in,
                              void* d_out, int out_size, void* d_ws, size_t ws_size,
                              hipStream_t stream) {
  (void)in_sizes; (void)n_in; (void)out_size; (void)ws_size;
  const float* query = (const float*)d_in[0];
  const float* key_  = (const float*)d_in[1];
  const float* value = (const float*)d_in[2];
  const int*   mask  = (const int*)d_in[3];
  const float* wq = (const float*)d_in[4];
  const float* bq = (const float*)d_in[5];
  const float* wk = (const float*)d_in[6];
  const float* bk = (const float*)d_in[7];
  const float* wv = (const float*)d_in[8];
  const float* bv = (const float*)d_in[9];
  const float* wo = (const float*)d_in[10];
  const float* bo = (const float*)d_in[11];
  float* out = (float*)d_out;

  char* ws = (char*)d_ws;
  const size_t SZX = (size_t)NB * NS * ND * 2;  // 8 MB (bf16 [4096,1024])
  const size_t SZW = (size_t)ND * ND * 2;       // 2 MB
  unsigned short* xq  = (unsigned short*)(ws);
  unsigned short* xk  = (unsigned short*)(ws + SZX);
  unsigned short* xv  = (unsigned short*)(ws + 2 * SZX);
  unsigned short* wqb = (unsigned short*)(ws + 3 * SZX);
  unsigned short* wkb = (unsigned short*)(ws + 3 * SZX + SZW);
  unsigned short* wvb = (unsigned short*)(ws + 3 * SZX + 2 * SZW);
  unsigned short* wob = (unsigned short*)(ws + 3 * SZX + 3 * SZW);
  unsigned short* Qb  = (unsigned short*)(ws + 3 * SZX + 4 * SZW);
  unsigned short* Kb  = (unsigned short*)(ws + 4 * SZX + 4 * SZW);
  unsigned short* Vt  = (unsigned short*)(ws + 5 * SZX + 4 * SZW);
  unsigned short* Ob  = (unsigned short*)(ws + 6 * SZX + 4 * SZW);
  unsigned long long* mb = (unsigned long long*)(ws + 7 * SZX + 4 * SZW);
  // total ws use: 7*8MB + 8MB + 1MB = 65 MB

  const int NX8 = NB * NS * ND / 8;  // 524288
  const int NW8 = ND * ND / 8;       // 131072
  cvt_kernel<<<2048, 256, 0, stream>>>(query, xq, NX8);
  cvt_kernel<<<2048, 256, 0, stream>>>(key_, xk, NX8);
  cvt_kernel<<<2048, 256, 0, stream>>>(value, xv, NX8);
  cvt_kernel<<<512, 256, 0, stream>>>(wq, wqb, NW8);
  cvt_kernel<<<512, 256, 0, stream>>>(wk, wkb, NW8);
  cvt_kernel<<<512, 256, 0, stream>>>(wv, wvb, NW8);
  cvt_kernel<<<512, 256, 0, stream>>>(wo, wob, NW8);
  maskbits_kernel<<<512, 256, 0, stream>>>(mask, mb);  // 131072 words

  qkv_kernel<<<dim3(8, 32, 3), 256, 0, stream>>>(xq, xk, xv, wqb, wkb, wvb,
                                                 bq, bk, bv, Qb, Kb, Vt);
  attn_kernel<<<dim3(16, 16, 2), 256, 0, stream>>>(Qb, Kb, Vt, mb, Ob);
  outproj_kernel<<<dim3(8, 32), 256, 0, stream>>>(Ob, wob, bo, out);
}